// Round 4
// baseline (351.155 us; speedup 1.0000x reference)
//
#include <hip/hip_runtime.h>

// Problem constants: B=4, S=2048 -> T=8192 tokens; H=512, F=2048, E=8, K=2.
#define T_TOKENS 8192
#define HD 512
#define FD 2048
#define NE 8
#define CAP 8192   // per-expert bucket capacity
#define CSTRIDE 32 // counter padding: one counter per 128B line

#define BM 128
// BK = 64 (8 chunks of 8 bf16); BN is a template param (128 FC1 / 64 FC2)

typedef __attribute__((ext_vector_type(8))) short short8;   // 8 bf16 = 4 VGPRs
typedef __attribute__((ext_vector_type(4))) float f32x4;    // MFMA accumulator

__device__ __forceinline__ ushort f2bf(float f) {
  union { float f; unsigned u; } v; v.f = f;
  unsigned u = v.u;
  return (ushort)((u + 0x7fffu + ((u >> 16) & 1u)) >> 16);  // RNE
}

// pack high-16 of two fp32 (bf16 truncation) into one dword: 1 v_perm_b32
__device__ __forceinline__ unsigned pack_trunc(float lo, float hi) {
  union { float f; unsigned u; } a, b; a.f = lo; b.f = hi;
  return __builtin_amdgcn_perm(b.u, a.u, 0x07060302);  // {hi[31:16], lo[31:16]}
}

// ---------------- fp32 -> bf16 bulk convert (x only now) ----------------
__global__ void cvt_bf16(const float4* __restrict__ src, ushort4* __restrict__ dst, int n4) {
  int i = blockIdx.x * blockDim.x + threadIdx.x;
  int st = gridDim.x * blockDim.x;
  for (; i < n4; i += st) {
    float4 v = src[i];
    ushort4 o;
    o.x = f2bf(v.x); o.y = f2bf(v.y); o.z = f2bf(v.z); o.w = f2bf(v.w);
    dst[i] = o;
  }
}

// ---------------- router: logits -> softmax -> top2 -> buckets ----------------
#define TPW 16
__global__ void router_kernel(const float* __restrict__ x, const float* __restrict__ rw,
                              float* __restrict__ probs_out, float* __restrict__ topk_out,
                              int* __restrict__ counts, int* __restrict__ bucket_tok,
                              float* __restrict__ bucket_w, int4* __restrict__ tok_info) {
  __shared__ int lcnt[NE];
  __shared__ int lbase[NE];
  __shared__ int ls_e0[64], ls_e1[64], ls_s0[64], ls_s1[64];
  __shared__ float ls_w0[64], ls_w1[64];

  int wave = threadIdx.x >> 6, lane = threadIdx.x & 63;
  if (threadIdx.x < NE) lcnt[threadIdx.x] = 0;
  __syncthreads();

  int tbase = blockIdx.x * 64;
  for (int it = 0; it < TPW; it++) {
    int lt = wave * TPW + it;
    int t = tbase + lt;
    float acc[NE];
#pragma unroll
    for (int e = 0; e < NE; e++) acc[e] = 0.f;
    const float* xr = x + (size_t)t * HD;
    for (int c = 0; c < HD; c += 64) {
      float xv = xr[c + lane];
#pragma unroll
      for (int e = 0; e < NE; e++) acc[e] += xv * rw[e * HD + c + lane];
    }
#pragma unroll
    for (int e = 0; e < NE; e++) {
#pragma unroll
      for (int s = 32; s > 0; s >>= 1) acc[e] += __shfl_xor(acc[e], s, 64);
    }
    if (lane == 0) {
      float m = acc[0];
#pragma unroll
      for (int e = 1; e < NE; e++) m = fmaxf(m, acc[e]);
      float p[NE], s = 0.f;
#pragma unroll
      for (int e = 0; e < NE; e++) { p[e] = expf(acc[e] - m); s += p[e]; }
      float inv = 1.f / s;
#pragma unroll
      for (int e = 0; e < NE; e++) { p[e] *= inv; probs_out[(size_t)t * NE + e] = p[e]; }
      int i0 = 0;
#pragma unroll
      for (int e = 1; e < NE; e++) if (p[e] > p[i0]) i0 = e;
      int i1 = (i0 == 0) ? 1 : 0;
#pragma unroll
      for (int e = 0; e < NE; e++) if (e != i0 && p[e] > p[i1]) i1 = e;
      float r = 1.f / (p[i0] + p[i1] + 1e-9f);
      topk_out[(size_t)t * 2 + 0] = (float)i0;
      topk_out[(size_t)t * 2 + 1] = (float)i1;
      ls_e0[lt] = i0; ls_e1[lt] = i1;
      ls_w0[lt] = p[i0] * r; ls_w1[lt] = p[i1] * r;
      ls_s0[lt] = atomicAdd(&lcnt[i0], 1);
      ls_s1[lt] = atomicAdd(&lcnt[i1], 1);
    }
  }
  __syncthreads();
  if (threadIdx.x < NE)
    lbase[threadIdx.x] = atomicAdd(&counts[threadIdx.x * CSTRIDE], lcnt[threadIdx.x]);
  __syncthreads();
  if (threadIdx.x < 64) {
    int lt = threadIdx.x, t = tbase + lt;
    int e0 = ls_e0[lt], e1 = ls_e1[lt];
    int g0 = lbase[e0] + ls_s0[lt];
    int g1 = lbase[e1] + ls_s1[lt];
    bucket_tok[e0 * CAP + g0] = t; bucket_w[e0 * CAP + g0] = ls_w0[lt];
    bucket_tok[e1 * CAP + g1] = t; bucket_w[e1 * CAP + g1] = ls_w1[lt];
    tok_info[t] = make_int4(e0, e1, g0, g1);
  }
}

__global__ void scan_kernel(const int* __restrict__ counts, int* __restrict__ offsets) {
  if (threadIdx.x == 0) {
    int o = 0;
#pragma unroll
    for (int e = 0; e < NE; e++) { offsets[e] = o; o += counts[e * CSTRIDE]; }
  }
}

// ---------------- grouped GEMM (bf16 MFMA 16x16x32), FC1 and FC2 ----------------
// R4: BK=64; VGPR-staged A(bf16) and B(fp32 -> trunc bf16) into XOR-swizzled
// [kchunk][row] LDS layout: cell(kc,row) at (kc*ROWS + (row^kc))*8 elems.
// Conflict-free on both ds_write_b128 and ds_read_b128 (2-way max = free).
// Weight cvt kernels eliminated: B read fp32 straight from input tensors.
template <int BN_, bool IS_FC1>
__global__ __launch_bounds__(256, 2)
void ffn_gemm(const ushort* __restrict__ Ab, const float* __restrict__ Bw,
              const float* __restrict__ bias, const int* __restrict__ counts,
              const int* __restrict__ offsets, const int* __restrict__ bucket_tok,
              const float* __restrict__ bucket_w, ushort* __restrict__ Aout,
              float* __restrict__ Yout, int KD, int ND) {
  constexpr int JW = BN_ / 32;         // j-tiles per wave: 4 (FC1) / 2 (FC2)
  constexpr int BCH_PT = BN_ / 32;     // B chunks per thread: 4 / 2

  int e = blockIdx.z;
  int cnt = counts[e * CSTRIDE];
  int m0 = blockIdx.y * BM;
  if (m0 >= cnt) return;
  int n0 = blockIdx.x * BN_;
  int off = offsets[e];

  __shared__ alignas(16) ushort As[8 * BM * 8];    // 16 KB
  __shared__ alignas(16) ushort Bs[8 * BN_ * 8];   // 16 KB / 8 KB

  int tid = threadIdx.x;
  int wid = tid >> 6, lid = tid & 63;
  int wm = wid >> 1, wn = wid & 1;
  int q = lid >> 4, l16 = lid & 15;

  int kc = tid & 7;        // k-chunk (identical for all u: 256 % 8 == 0)
  int rbase = tid >> 3;    // row for u=0; +32 per u

  const ushort* aptr[4];
  int aoff[4];
#pragma unroll
  for (int u = 0; u < 4; u++) {
    int m = rbase + u * 32;
    int mr = min(m0 + m, cnt - 1);
    int row = IS_FC1 ? bucket_tok[e * CAP + mr] : (off + mr);
    aptr[u] = Ab + (size_t)row * KD + kc * 8;
    aoff[u] = (kc * BM + (m ^ kc)) * 8;
  }
  const float* bptr[BCH_PT];
  int boff[BCH_PT];
#pragma unroll
  for (int u = 0; u < BCH_PT; u++) {
    int n = rbase + u * 32;
    bptr[u] = Bw + ((size_t)e * ND + n0 + n) * KD + kc * 8;
    boff[u] = (kc * BN_ + (n ^ kc)) * 8;
  }

  f32x4 acc[4][JW] = {};

  for (int k0 = 0; k0 < KD; k0 += 64) {
    uint4 av[4];
#pragma unroll
    for (int u = 0; u < 4; u++) av[u] = *(const uint4*)(aptr[u] + k0);
    float4 bv0[BCH_PT], bv1[BCH_PT];
#pragma unroll
    for (int u = 0; u < BCH_PT; u++) {
      bv0[u] = *(const float4*)(bptr[u] + k0);
      bv1[u] = *(const float4*)(bptr[u] + k0 + 4);
    }
#pragma unroll
    for (int u = 0; u < 4; u++) *(uint4*)&As[aoff[u]] = av[u];
#pragma unroll
    for (int u = 0; u < BCH_PT; u++) {
      uint4 o;
      o.x = pack_trunc(bv0[u].x, bv0[u].y);
      o.y = pack_trunc(bv0[u].z, bv0[u].w);
      o.z = pack_trunc(bv1[u].x, bv1[u].y);
      o.w = pack_trunc(bv1[u].z, bv1[u].w);
      *(uint4*)&Bs[boff[u]] = o;
    }
    __syncthreads();
#pragma unroll
    for (int t = 0; t < 2; t++) {
      int kcc = t * 4 + q;
      short8 af[4], bfr[JW];
#pragma unroll
      for (int i = 0; i < 4; i++) {
        int m = wm * 64 + i * 16 + l16;
        af[i] = *(const short8*)&As[((kcc * BM) + (m ^ kcc)) * 8];
      }
#pragma unroll
      for (int j = 0; j < JW; j++) {
        int n = wn * (16 * JW) + j * 16 + l16;
        bfr[j] = *(const short8*)&Bs[((kcc * BN_) + (n ^ kcc)) * 8];
      }
#pragma unroll
      for (int i = 0; i < 4; i++)
#pragma unroll
        for (int j = 0; j < JW; j++)
          acc[i][j] = __builtin_amdgcn_mfma_f32_16x16x32_bf16(af[i], bfr[j], acc[i][j], 0, 0, 0);
    }
    __syncthreads();
  }

  // ---- epilogue through LDS (reuses As region) ----
  float bcol[JW];
#pragma unroll
  for (int j = 0; j < JW; j++)
    bcol[j] = bias[(size_t)e * ND + n0 + wn * (16 * JW) + j * 16 + l16];

  if (IS_FC1) {
    ushort* Ct = As;  // [32][136] bf16 = 8704 B
#pragma unroll
    for (int i = 0; i < 4; i++) {
      __syncthreads();
#pragma unroll
      for (int j = 0; j < JW; j++)
#pragma unroll
        for (int r = 0; r < 4; r++) {
          float v = acc[i][j][r] + bcol[j];
          float g = 0.5f * v * (1.0f + erff(v * 0.70710678118654752f));
          Ct[(wm * 16 + q * 4 + r) * 136 + wn * 64 + j * 16 + l16] = f2bf(g);
        }
      __syncthreads();
#pragma unroll
      for (int u = 0; u < 2; u++) {
        int c = tid + u * 256;            // 512 chunks of 8 bf16
        int ml = c >> 4, cc = c & 15;
        int gm = m0 + (ml >> 4) * 64 + i * 16 + (ml & 15);
        if (gm < cnt)
          *(uint4*)&Aout[(size_t)(off + gm) * ND + n0 + cc * 8] =
              *(const uint4*)&Ct[ml * 136 + cc * 8];
      }
    }
  } else {
    float* Ct = (float*)As;  // [32][68] fp32 = 8704 B
#pragma unroll
    for (int i = 0; i < 4; i++) {
      __syncthreads();
#pragma unroll
      for (int r = 0; r < 4; r++) {
        int gm = m0 + wm * 64 + i * 16 + q * 4 + r;
        float wgt = bucket_w[e * CAP + min(gm, cnt - 1)];
#pragma unroll
        for (int j = 0; j < JW; j++)
          Ct[(wm * 16 + q * 4 + r) * 68 + wn * 32 + j * 16 + l16] = wgt * (acc[i][j][r] + bcol[j]);
      }
      __syncthreads();
#pragma unroll
      for (int u = 0; u < 2; u++) {
        int c = tid + u * 256;            // 512 chunks of 4 floats (32 rows x 64 cols)
        int ml = c >> 4, cc = c & 15;
        int gm = m0 + (ml >> 4) * 64 + i * 16 + (ml & 15);
        if (gm < cnt)
          *(float4*)&Yout[(size_t)(off + gm) * ND + n0 + cc * 4] =
              *(const float4*)&Ct[ml * 68 + cc * 4];
      }
    }
  }
}

// ---------------- combine: out[t] = Y[row(e0,s0)] + Y[row(e1,s1)] ----------------
__global__ void combine_kernel(const float4* __restrict__ Y, const int4* __restrict__ tok_info,
                               const int* __restrict__ offsets, float4* __restrict__ out) {
  int t = blockIdx.x;
  int4 ti = tok_info[t];
  int g0 = offsets[ti.x] + ti.z;
  int g1 = offsets[ti.y] + ti.w;
  int i = threadIdx.x;  // 128 threads, H/4 = 128 float4 per row
  float4 a = Y[(size_t)g0 * (HD / 4) + i];
  float4 b = Y[(size_t)g1 * (HD / 4) + i];
  out[(size_t)t * (HD / 4) + i] = make_float4(a.x + b.x, a.y + b.y, a.z + b.z, a.w + b.w);
}

extern "C" void kernel_launch(void* const* d_in, const int* in_sizes, int n_in,
                              void* d_out, int out_size, void* d_ws, size_t ws_size,
                              hipStream_t stream) {
  const float* x    = (const float*)d_in[0];
  const float* rw   = (const float*)d_in[1];
  const float* fc1w = (const float*)d_in[2];
  const float* fc1b = (const float*)d_in[3];
  const float* fc2w = (const float*)d_in[4];
  const float* fc2b = (const float*)d_in[5];

  float* out   = (float*)d_out;
  float* probs = out + (size_t)T_TOKENS * HD;
  float* topk  = probs + (size_t)T_TOKENS * NE;

  char* p = (char*)d_ws;
  auto carve = [&](size_t bytes) { char* r = p; p += (bytes + 255) & ~(size_t)255; return r; };
  int*    counts     = (int*)carve(NE * CSTRIDE * sizeof(int));
  int*    offsets    = (int*)carve(NE * sizeof(int));
  int*    bucket_tok = (int*)carve((size_t)NE * CAP * sizeof(int));
  float*  bucket_w   = (float*)carve((size_t)NE * CAP * sizeof(float));
  int4*   tok_info   = (int4*)carve((size_t)T_TOKENS * sizeof(int4));
  ushort* xb   = (ushort*)carve((size_t)T_TOKENS * HD * 2);
  ushort* Abuf = (ushort*)carve((size_t)T_TOKENS * 2 * FD * 2);  // compact GELU out, bf16
  float*  Y    = (float*)carve((size_t)T_TOKENS * 2 * HD * 4);   // gated FC2 rows, fp32

  hipMemsetAsync(counts, 0, NE * CSTRIDE * sizeof(int), stream);
  cvt_bf16<<<2048, 256, 0, stream>>>((const float4*)x, (ushort4*)xb, T_TOKENS * HD / 4);
  router_kernel<<<T_TOKENS / 64, 256, 0, stream>>>(x, rw, probs, topk, counts, bucket_tok,
                                                   bucket_w, tok_info);
  scan_kernel<<<1, 64, 0, stream>>>(counts, offsets);
  ffn_gemm<128, true><<<dim3(FD / 128, CAP / BM, NE), 256, 0, stream>>>(
      xb, fc1w, fc1b, counts, offsets, bucket_tok, bucket_w, Abuf, nullptr, HD, FD);
  ffn_gemm<64, false><<<dim3(HD / 64, CAP / BM, NE), 256, 0, stream>>>(
      Abuf, fc2w, fc2b, counts, offsets, bucket_tok, bucket_w, nullptr, Y, FD, HD);
  combine_kernel<<<T_TOKENS, 128, 0, stream>>>((const float4*)Y, tok_info, offsets, (float4*)out);
}